// Round 9
// baseline (564.244 us; speedup 1.0000x reference)
//
#include <hip/hip_runtime.h>

// NaiveCustomLSTM: V block-diagonal (20 blocks of 32), U (nearly) diagonal.
// => 2560 independent 32-wide LSTMs (128 batch x 20 blocks), 512 steps.
// One unit per wave (grid 2560, 10 waves/CU). Lanes 0-31: gates {i,f} for
// col n; lanes 32-63: gates {g,o} (R11 layout, proven absmax-exact).
//
// R16: h-broadcast via 32x v_readlane -> SGPRs. R11-R15 measured both
// failure regimes: (a) DS-pipe throughput saturation at >=120 DS-ops/CU/step
// (R11 1275 cyc, R14 1725, R15 1478) and (b) the DS-latency serial chain
// ~1240 cyc for low-DS variants (R12: wall = T_chain since waves overlap).
// readlane is VALU: no DS pipe use, ~4 cyc latency, results are wave-uniform
// scalars -> legal as the one SGPR source of v_pk_fma_f32 (SGPR pair
// s[40+2kp:41+2kp], even-aligned). This works ONLY in the 1-unit/wave
// layout (h uniform across the wave) -- the R12 2-batch layout would need
// different SGPRs per half (impossible). DS remaining: 2 tail bpermutes
// per step (cross-half exchange) = 20 DS/CU/step, trivial.
// x also via readlane (index SGPR s25). Weights stay pinned v96-v159 via
// asm prologue reads from LDS staging. FP op sequence == R11 -> absmax
// must be exactly 2.441406e-4 (built-in addressing self-check).
// Predicted regime: issue-bound, I ~= 276 cyc/wave-step, W = 2.5/SIMD.

#define TT 512
#define HN 640
#define BN 128

typedef unsigned int u32x4 __attribute__((ext_vector_type(4)));

__global__ __attribute__((amdgpu_flat_work_group_size(64, 64)))
void lstm_kernel(
    const float* __restrict__ x,
    const float* __restrict__ Ui, const float* __restrict__ Vi, const float* __restrict__ bi,
    const float* __restrict__ Uf, const float* __restrict__ Vf, const float* __restrict__ bf,
    const float* __restrict__ Uc, const float* __restrict__ Vc, const float* __restrict__ bc,
    const float* __restrict__ Uo, const float* __restrict__ Vo, const float* __restrict__ bo,
    float* __restrict__ out) {
  // LDS: weight staging only (prologue). 64 lanes x 68-float stride (272B):
  // [0..31] gate1 weights (Bs*Vi / Bg*Vc), [32..63] gate2 (Bs*Vf / Bs*Vo),
  // [64..67] pad.
  __shared__ __align__(16) float lds[4352];

  const int unit = blockIdx.x;   // 0..2559
  const int lane = threadIdx.x;  // 0..63
  const int j = unit >> 7;       // hidden block 0..19
  const int b = unit & 127;      // batch
  const int gp = lane >> 5;      // 0: gates {i,f} ; 1: gates {g,o}
  const int n = lane & 31;
  const int col = j * 32 + n;

  const float LOG2E = 1.44269504088896340736f;
  const float Bs = -LOG2E;        // sigmoid scale
  const float Bg = -2.f * LOG2E;  // tanh scale
  const float B1 = gp ? Bg : Bs;

  // Stage pre-scaled V-weight columns (each lane stages its own gates).
  {
    const float* W1 = gp ? Vc : Vi;   // gate1: i / g
    const float* W2 = gp ? Vo : Vf;   // gate2: f / o
    for (int k = 0; k < 32; ++k) {
      const int r = (j * 32 + k) * HN + col;
      lds[lane * 68 + k]      = B1 * W1[r];
      lds[lane * 68 + 32 + k] = Bs * W2[r];
    }
  }

  // U mask structure -> features f1, f2i and effective input weights.
  int f1 = 0, f2i = 0;
  if (j < 16) { f1 = f2i = j; if (j == 0) f2i = 1; else if (j == 2) f2i = 3; }
  auto uw = [&](const float* __restrict__ U, float& w1, float& w2) {
    w1 = 0.f; w2 = 0.f;
    if (j < 16) {
      w1 = U[j * HN + col];
      if (j == 0)      { w1 += U[16 * HN + col]; w2 = U[17 * HN + col]; }
      else if (j == 2) { w1 += U[18 * HN + col]; w2 = U[19 * HN + col]; }
    }
  };
  float a1w, a2w, b1w, b2w;
  uw(gp ? Uc : Ui, a1w, a2w);   // gate1 (i or g)
  uw(gp ? Uo : Uf, b1w, b2w);   // gate2 (f or o)
  const float ws11 = B1 * a1w, ws21 = B1 * a2w;
  const float bs1  = B1 * (gp ? bc[col] : bi[col]);
  const float ws12 = Bs * b1w, ws22 = Bs * b2w;
  const float bs2  = Bs * (gp ? bo[col] : bf[col]);
  const float Ac1 = gp ? 2.f : 1.f;
  const float Cc1 = gp ? -1.f : 0.f;

  const unsigned zb  = (unsigned)(unsigned long long)&lds[0];
  const unsigned wrd = zb + (unsigned)lane * 272u;
  const unsigned swz = (unsigned)((lane ^ 32) & 63) * 4u;  // tail exchange

  u32x4 xsrd, osrd;
  { const unsigned long long a = (unsigned long long)x;
    xsrd.x = (unsigned)a; xsrd.y = (unsigned)(a >> 32);
    xsrd.z = (unsigned)(BN * TT * 16 * 4); xsrd.w = 0x00020000u; }
  { const unsigned long long a = (unsigned long long)out;
    osrd.x = (unsigned)a; osrd.y = (unsigned)(a >> 32);
    osrd.z = (unsigned)((BN * TT * HN + 2 * BN * HN) * 4); osrd.w = 0x00020000u; }

  // h stores: lanes 0-31 valid; hi lanes OOB voffset -> dropped by SRD.
  unsigned voff = (lane < 32) ? (unsigned)((b * TT * HN + col) * 4)
                              : 0x60000000u;
  // x rows: lane holds t = chunk*64 + lane, feature f1 (f2 via sfd).
  unsigned xv = (unsigned)(((b * TT + lane) * 16 + f1) * 4);
  const int sfd = (f2i - f1) * 4;

  float h = 0.f, c = 0.f;

  asm volatile(
    // ---- prologue: weights LDS -> v[96:159]; x chunk 0+1 loads ----
    "s_waitcnt lgkmcnt(0)\n\t"
    "ds_read_b128 v[96:99],   %[wrd]\n\t"
    "ds_read_b128 v[100:103], %[wrd] offset:16\n\t"
    "ds_read_b128 v[104:107], %[wrd] offset:32\n\t"
    "ds_read_b128 v[108:111], %[wrd] offset:48\n\t"
    "ds_read_b128 v[112:115], %[wrd] offset:64\n\t"
    "ds_read_b128 v[116:119], %[wrd] offset:80\n\t"
    "ds_read_b128 v[120:123], %[wrd] offset:96\n\t"
    "ds_read_b128 v[124:127], %[wrd] offset:112\n\t"
    "ds_read_b128 v[128:131], %[wrd] offset:128\n\t"
    "ds_read_b128 v[132:135], %[wrd] offset:144\n\t"
    "ds_read_b128 v[136:139], %[wrd] offset:160\n\t"
    "ds_read_b128 v[140:143], %[wrd] offset:176\n\t"
    "ds_read_b128 v[144:147], %[wrd] offset:192\n\t"
    "ds_read_b128 v[148:151], %[wrd] offset:208\n\t"
    "ds_read_b128 v[152:155], %[wrd] offset:224\n\t"
    "ds_read_b128 v[156:159], %[wrd] offset:240\n\t"
    "buffer_load_dword v24, %[xv], %[xsrd], 0 offen\n\t"
    "buffer_load_dword v25, %[xv], %[xsrd], %[sfd] offen\n\t"
    "v_add_u32 %[xv], 0x1000, %[xv]\n\t"
    "buffer_load_dword v28, %[xv], %[xsrd], 0 offen\n\t"
    "buffer_load_dword v29, %[xv], %[xsrd], %[sfd] offen\n\t"
    "s_waitcnt lgkmcnt(0)\n\t"
    "s_waitcnt vmcnt(2)\n\t"              // v24/v25 resident
    "s_mov_b32 s21, 8\n\t"
    "Louter%=:\n\t"
    "s_mov_b32 s25, 0\n\t"
    "s_mov_b32 s20, 64\n\t"
    "Lbody%=:\n\t"
    // x select: scalar readlane by step index s25
    "v_readlane_b32 s26, v24, s25\n\t"
    "v_readlane_b32 s27, v25, s25\n\t"
    "s_add_u32 s25, s25, 1\n\t"
    // h broadcast: 32 readlanes -> s[40:71] (VALU, no DS pipe)
    "v_readlane_b32 s40, %[h], 0\n\t"
    "v_readlane_b32 s41, %[h], 1\n\t"
    "v_readlane_b32 s42, %[h], 2\n\t"
    "v_readlane_b32 s43, %[h], 3\n\t"
    "v_readlane_b32 s44, %[h], 4\n\t"
    "v_readlane_b32 s45, %[h], 5\n\t"
    "v_readlane_b32 s46, %[h], 6\n\t"
    "v_readlane_b32 s47, %[h], 7\n\t"
    "v_readlane_b32 s48, %[h], 8\n\t"
    "v_readlane_b32 s49, %[h], 9\n\t"
    "v_readlane_b32 s50, %[h], 10\n\t"
    "v_readlane_b32 s51, %[h], 11\n\t"
    "v_readlane_b32 s52, %[h], 12\n\t"
    "v_readlane_b32 s53, %[h], 13\n\t"
    "v_readlane_b32 s54, %[h], 14\n\t"
    "v_readlane_b32 s55, %[h], 15\n\t"
    "v_readlane_b32 s56, %[h], 16\n\t"
    "v_readlane_b32 s57, %[h], 17\n\t"
    "v_readlane_b32 s58, %[h], 18\n\t"
    "v_readlane_b32 s59, %[h], 19\n\t"
    "v_readlane_b32 s60, %[h], 20\n\t"
    "v_readlane_b32 s61, %[h], 21\n\t"
    "v_readlane_b32 s62, %[h], 22\n\t"
    "v_readlane_b32 s63, %[h], 23\n\t"
    "v_readlane_b32 s64, %[h], 24\n\t"
    "v_readlane_b32 s65, %[h], 25\n\t"
    "v_readlane_b32 s66, %[h], 26\n\t"
    "v_readlane_b32 s67, %[h], 27\n\t"
    "v_readlane_b32 s68, %[h], 28\n\t"
    "v_readlane_b32 s69, %[h], 29\n\t"
    "v_readlane_b32 s70, %[h], 30\n\t"
    "v_readlane_b32 s71, %[h], 31\n\t"
    // per-lane scaled x contribution (weights applied after broadcast)
    "v_mov_b32 v36, %[bs1]\n\t"
    "v_fmac_f32 v36, s26, %[w11]\n\t"
    "v_fmac_f32 v36, s27, %[w21]\n\t"
    "v_mov_b32 v37, %[bs2]\n\t"
    "v_fmac_f32 v37, s26, %[w12]\n\t"
    "v_fmac_f32 v37, s27, %[w22]\n\t"
    // seeds: chain0A = {sx1, 0}, chain0B = {sx2, 0}; chain1 first-touch mul
    "v_mov_b32 v40, v36\n\t"
    "v_mov_b32 v41, 0\n\t"
    "v_mov_b32 v44, v37\n\t"
    "v_mov_b32 v45, 0\n\t"
    // 32x v_pk_fma_f32: kp pairs {2kp,2kp+1}, even kp -> chain0, odd -> 1
    "v_pk_fma_f32 v[40:41], v[96:97],   s[40:41], v[40:41]\n\t"
    "v_pk_fma_f32 v[44:45], v[128:129], s[40:41], v[44:45]\n\t"
    "v_pk_mul_f32 v[42:43], v[98:99],   s[42:43]\n\t"
    "v_pk_mul_f32 v[46:47], v[130:131], s[42:43]\n\t"
    "v_pk_fma_f32 v[40:41], v[100:101], s[44:45], v[40:41]\n\t"
    "v_pk_fma_f32 v[44:45], v[132:133], s[44:45], v[44:45]\n\t"
    "v_pk_fma_f32 v[42:43], v[102:103], s[46:47], v[42:43]\n\t"
    "v_pk_fma_f32 v[46:47], v[134:135], s[46:47], v[46:47]\n\t"
    "v_pk_fma_f32 v[40:41], v[104:105], s[48:49], v[40:41]\n\t"
    "v_pk_fma_f32 v[44:45], v[136:137], s[48:49], v[44:45]\n\t"
    "v_pk_fma_f32 v[42:43], v[106:107], s[50:51], v[42:43]\n\t"
    "v_pk_fma_f32 v[46:47], v[138:139], s[50:51], v[46:47]\n\t"
    "v_pk_fma_f32 v[40:41], v[108:109], s[52:53], v[40:41]\n\t"
    "v_pk_fma_f32 v[44:45], v[140:141], s[52:53], v[44:45]\n\t"
    "v_pk_fma_f32 v[42:43], v[110:111], s[54:55], v[42:43]\n\t"
    "v_pk_fma_f32 v[46:47], v[142:143], s[54:55], v[46:47]\n\t"
    "v_pk_fma_f32 v[40:41], v[112:113], s[56:57], v[40:41]\n\t"
    "v_pk_fma_f32 v[44:45], v[144:145], s[56:57], v[44:45]\n\t"
    "v_pk_fma_f32 v[42:43], v[114:115], s[58:59], v[42:43]\n\t"
    "v_pk_fma_f32 v[46:47], v[146:147], s[58:59], v[46:47]\n\t"
    "v_pk_fma_f32 v[40:41], v[116:117], s[60:61], v[40:41]\n\t"
    "v_pk_fma_f32 v[44:45], v[148:149], s[60:61], v[44:45]\n\t"
    "v_pk_fma_f32 v[42:43], v[118:119], s[62:63], v[42:43]\n\t"
    "v_pk_fma_f32 v[46:47], v[150:151], s[62:63], v[46:47]\n\t"
    "v_pk_fma_f32 v[40:41], v[120:121], s[64:65], v[40:41]\n\t"
    "v_pk_fma_f32 v[44:45], v[152:153], s[64:65], v[44:45]\n\t"
    "v_pk_fma_f32 v[42:43], v[122:123], s[66:67], v[42:43]\n\t"
    "v_pk_fma_f32 v[46:47], v[154:155], s[66:67], v[46:47]\n\t"
    "v_pk_fma_f32 v[40:41], v[124:125], s[68:69], v[40:41]\n\t"
    "v_pk_fma_f32 v[44:45], v[156:157], s[68:69], v[44:45]\n\t"
    "v_pk_fma_f32 v[42:43], v[126:127], s[70:71], v[42:43]\n\t"
    "v_pk_fma_f32 v[46:47], v[158:159], s[70:71], v[46:47]\n\t"
    // reduce + activations (FP sequence identical to R11)
    "v_pk_add_f32 v[40:41], v[40:41], v[42:43]\n\t"
    "v_pk_add_f32 v[44:45], v[44:45], v[46:47]\n\t"
    "v_add_f32 v80, v40, v41\n\t"         // a1
    "v_add_f32 v81, v44, v45\n\t"         // a2
    "v_exp_f32 v80, v80\n\t"
    "v_exp_f32 v81, v81\n\t"
    "s_nop 1\n\t"
    "v_add_f32 v80, 1.0, v80\n\t"
    "v_add_f32 v81, 1.0, v81\n\t"
    "v_rcp_f32 v80, v80\n\t"
    "v_rcp_f32 v81, v81\n\t"
    "s_nop 1\n\t"
    "v_fma_f32 v80, %[ac1], v80, %[cc1]\n\t"  // g1
    "ds_bpermute_b32 v82, %[swz], v80\n\t"    // p1 (cross-half)
    "ds_bpermute_b32 v83, %[swz], v81\n\t"    // p2
    "s_waitcnt lgkmcnt(0)\n\t"
    "v_mul_f32 v84, v80, v82\n\t"             // g1*p1
    "v_fma_f32 %[c], v81, %[c], v84\n\t"      // c = g2*c + g1*p1
    "v_mul_f32 v85, 0xc038aa3b, %[c]\n\t"     // -2*log2e * c
    "v_exp_f32 v85, v85\n\t"
    "s_nop 1\n\t"
    "v_add_f32 v85, 1.0, v85\n\t"
    "v_rcp_f32 v85, v85\n\t"
    "s_nop 1\n\t"
    "v_fma_f32 v85, 2.0, v85, -1.0\n\t"       // tanh(c)
    "v_mul_f32 %[h], v83, v85\n\t"            // h = p2 * tanh(c)
    "buffer_store_dword %[h], %[voff], %[osrd], 0 offen\n\t"
    "v_add_u32 %[voff], 0xa00, %[voff]\n\t"
    "s_sub_u32 s20, s20, 1\n\t"
    "s_cmp_lg_u32 s20, 0\n\t"
    "s_cbranch_scc1 Lbody%=\n\t"
    // ---- chunk boundary: rotate x, prefetch next ----
    "s_waitcnt vmcnt(0)\n\t"
    "v_mov_b32 v24, v28\n\t"
    "v_mov_b32 v25, v29\n\t"
    "v_add_u32 %[xv], 0x1000, %[xv]\n\t"
    "buffer_load_dword v28, %[xv], %[xsrd], 0 offen\n\t"
    "buffer_load_dword v29, %[xv], %[xsrd], %[sfd] offen\n\t"
    "s_sub_u32 s21, s21, 1\n\t"
    "s_cmp_lg_u32 s21, 0\n\t"
    "s_cbranch_scc1 Louter%=\n\t"
    : [h]"+v"(h), [c]"+v"(c), [voff]"+v"(voff), [xv]"+v"(xv)
    : [wrd]"v"(wrd), [swz]"v"(swz),
      [w11]"v"(ws11), [w21]"v"(ws21), [bs1]"v"(bs1),
      [w12]"v"(ws12), [w22]"v"(ws22), [bs2]"v"(bs2),
      [ac1]"v"(Ac1), [cc1]"v"(Cc1),
      [xsrd]"s"(xsrd), [osrd]"s"(osrd), [sfd]"s"(sfd)
    : "memory", "scc",
      "s20","s21","s25","s26","s27",
      "s40","s41","s42","s43","s44","s45","s46","s47",
      "s48","s49","s50","s51","s52","s53","s54","s55",
      "s56","s57","s58","s59","s60","s61","s62","s63",
      "s64","s65","s66","s67","s68","s69","s70","s71",
      "v24","v25","v28","v29","v36","v37",
      "v40","v41","v42","v43","v44","v45","v46","v47",
      "v80","v81","v82","v83","v84","v85",
      "v96","v97","v98","v99","v100","v101","v102","v103",
      "v104","v105","v106","v107","v108","v109","v110","v111",
      "v112","v113","v114","v115","v116","v117","v118","v119",
      "v120","v121","v122","v123","v124","v125","v126","v127",
      "v128","v129","v130","v131","v132","v133","v134","v135",
      "v136","v137","v138","v139","v140","v141","v142","v143",
      "v144","v145","v146","v147","v148","v149","v150","v151",
      "v152","v153","v154","v155","v156","v157","v158","v159");

  if (lane < 32) {
    out[BN * TT * HN + b * HN + col] = h;             // h_t
    out[BN * TT * HN + BN * HN + b * HN + col] = c;   // c_t
  }
}

extern "C" void kernel_launch(void* const* d_in, const int* in_sizes, int n_in,
                              void* d_out, int out_size, void* d_ws, size_t ws_size,
                              hipStream_t stream) {
  (void)in_sizes; (void)n_in; (void)d_ws; (void)ws_size; (void)out_size;
  const float* x  = (const float*)d_in[0];
  const float* Ui = (const float*)d_in[1];
  const float* Vi = (const float*)d_in[2];
  const float* bi = (const float*)d_in[3];
  const float* Uf = (const float*)d_in[4];
  const float* Vf = (const float*)d_in[5];
  const float* bf = (const float*)d_in[6];
  const float* Uc = (const float*)d_in[7];
  const float* Vc = (const float*)d_in[8];
  const float* bc = (const float*)d_in[9];
  const float* Uo = (const float*)d_in[10];
  const float* Vo = (const float*)d_in[11];
  const float* bo = (const float*)d_in[12];
  float* out = (float*)d_out;

  dim3 grid(2560);  // one unit per wave -> 10 waves/CU
  dim3 block(64);
  hipLaunchKernelGGL(lstm_kernel, grid, block, 0, stream,
                     x, Ui, Vi, bi, Uf, Vf, bf, Uc, Vc, bc, Uo, Vo, bo, out);
}

// Round 13
// 394.547 us; speedup vs baseline: 1.4301x; 1.4301x over previous
//
#include <hip/hip_runtime.h>

// NaiveCustomLSTM: V block-diagonal (20 blocks of 32), U (nearly) diagonal.
// => 2560 independent 32-wide LSTMs (128 batch x 20 blocks), 512 steps.
// One unit per wave (grid 2560 -> 2.5 waves/SIMD). Lanes 0-31: gates {i,f}
// for n=lane; lanes 32-63: gates {g,o} (R11 structure, byte-identical
// except the three rcp sites).
//
// R17 (3rd resubmit; three consecutive infra failures -- 2x
// GPUAcquisitionTimeout, 1x container-failed-twice -- never measured):
// R11 + Newton-rcp, ONE variable. Cross-round accounting
// (R7/R11/R12/R15/R16 all ~125-150 cyc/unit-step/CU) pins the busy model:
// pk_fma 4 cyc, v_exp/v_rcp ~32 busy-cyc each (wave64), misc 2 cyc. R11 at
// W=2.5 is near VALU-throughput-bound (busy ~975 of 1275 wall, 61%
// VALUBusy) and trans is the largest term (6 wave-ops x 32 = 192
// cyc/unit-step > the 64 MACs' 128). R13 tested Newton only on the W=1.25
// chain-bound R12 base (where +chain latency loses) AND bundled it with
// staged waits -> its regression doesn't condemn Newton in the busy-bound
// regime. R16's lesson: readlane SGPR broadcast costs ~23 cyc/op
// (VALU->SGPR->VALU scoreboard), permanently off the table; LDS write +
// 8x b128 broadcast stays. Newton (magic seed 0x7ef0a3d2, 2 iters, rel err
// ~1.4e-6, correctness proven by R13's pass): replaces 3 v_rcp (96 busy)
// with ~30 busy-cyc of plain VALU. Predicted: 1275 -> ~1110 cyc/SIMD-step
// (~232 us kernel), VALUBusy 61 -> ~70%. If flat at ~61%/265us: wall is
// DS-pipe/stall serialization -> next lever is f16 h-broadcast.

#define TT 512
#define HN 640
#define BN 128

typedef float f2 __attribute__((ext_vector_type(2)));
typedef unsigned int u32x4 __attribute__((ext_vector_type(4)));

__global__ __attribute__((amdgpu_flat_work_group_size(64, 64)))
void lstm_kernel(
    const float* __restrict__ x,
    const float* __restrict__ Ui, const float* __restrict__ Vi, const float* __restrict__ bi,
    const float* __restrict__ Uf, const float* __restrict__ Vf, const float* __restrict__ bf,
    const float* __restrict__ Uc, const float* __restrict__ Vc, const float* __restrict__ bc,
    const float* __restrict__ Uo, const float* __restrict__ Vo, const float* __restrict__ bo,
    float* __restrict__ out) {
  // [0..63]: h broadcast ([0..31] valid, [32..63] junk sink);
  // [64..127]: x1 for the current 64-step chunk; [128..191]: x2.
  __shared__ __align__(16) float hsh[192];

  const int unit = blockIdx.x;   // 0..2559
  const int lane = threadIdx.x;  // 0..63
  const int j = unit >> 7;       // hidden block 0..19
  const int b = unit & 127;      // batch
  const int gp = lane >> 5;      // 0: gates i,f ; 1: gates g,o
  const int n = lane & 31;
  const int col = j * 32 + n;

  const float* UG1 = gp ? Uc : Ui;
  const float* UG2 = gp ? Uo : Uf;
  const float* VG1 = gp ? Vc : Vi;
  const float* VG2 = gp ? Vo : Vf;
  const float* bG1 = gp ? bc : bi;
  const float* bG2 = gp ? bo : bf;

  const float LOG2E = 1.44269504088896340736f;
  // gate1: lo = sigmoid(i) (scale -log2e); hi = tanh(g) (scale -2log2e)
  // gate2: sigmoid (f / o) for both halves.
  const float B1 = gp ? (-2.f * LOG2E) : -LOG2E;
  const float B2 = -LOG2E;
  const float Ac1 = gp ? 2.f : 1.f;
  const float Cc1 = gp ? -1.f : 0.f;

  // Effective input weights for this block (from U mask structure).
  float w11 = 0.f, w21 = 0.f, w12 = 0.f, w22 = 0.f;
  int f1 = 0, f2i = 0;
  if (j < 16) {
    f1 = f2i = j;
    w11 = UG1[j * HN + col];
    w12 = UG2[j * HN + col];
    if (j == 0) {
      w11 += UG1[16 * HN + col]; w12 += UG2[16 * HN + col];
      w21  = UG1[17 * HN + col]; w22  = UG2[17 * HN + col];
      f2i = 1;
    } else if (j == 2) {
      w11 += UG1[18 * HN + col]; w12 += UG2[18 * HN + col];
      w21  = UG1[19 * HN + col]; w22  = UG2[19 * HN + col];
      f2i = 3;
    }
  }
  // Pre-scale per-lane input weights/bias by the exp2 factor (stays per-lane).
  const float ws11 = B1 * w11, ws21 = B1 * w21, bs1 = B1 * bG1[col];
  const float ws12 = B2 * w12, ws22 = B2 * w22, bs2 = B2 * bG2[col];

  // Recurrent weight columns, pre-scaled, paired over k:
  // wA[kp] = {B1*V1[2kp,col], B1*V1[2kp+1,col]}, wB likewise with B2*V2.
  f2 wA[16], wB[16];
#pragma unroll
  for (int kp = 0; kp < 16; ++kp) {
    wA[kp].x = B1 * VG1[(j * 32 + 2 * kp) * HN + col];
    wA[kp].y = B1 * VG1[(j * 32 + 2 * kp + 1) * HN + col];
    wB[kp].x = B2 * VG2[(j * 32 + 2 * kp) * HN + col];
    wB[kp].y = B2 * VG2[(j * 32 + 2 * kp + 1) * HN + col];
  }

  // LDS byte offsets (low 32 bits of a generic shared address = LDS offset).
  const unsigned zb    = (unsigned)(unsigned long long)&hsh[0];
  const unsigned laddr = zb + (unsigned)lane * 4u;
  const unsigned xbase = zb + 256u;
  const unsigned swz   = (unsigned)((lane ^ 32) & 63) * 4u;  // ds_bpermute sel

  // Buffer SRD over the whole out buffer; junk lanes store OOB (dropped).
  const unsigned out_bytes = (unsigned)((BN * TT * HN + 2 * BN * HN) * 4);
  const unsigned long long outa = (unsigned long long)out;
  u32x4 srd;
  srd.x = (unsigned)outa;
  srd.y = (unsigned)(outa >> 32);
  srd.z = out_bytes;
  srd.w = 0x00020000u;
  unsigned voff = (lane < 32) ? (unsigned)((b * TT * HN + col) * 4)
                              : 0x60000000u;  // far beyond num_records

  float h = 0.f, c = 0.f;  // valid in lanes 0-31; upper half carries junk

  // Prime first chunk's x (lane-uniform in n: only t = i*64+lane varies).
  float nx1 = x[(b * TT + lane) * 16 + f1];
  float nx2 = x[(b * TT + lane) * 16 + f2i];

#pragma unroll 1
  for (int i = 0; i < 8; ++i) {
    hsh[64 + lane]  = nx1;   // stage this chunk's x for broadcast reads
    hsh[128 + lane] = nx2;
    if (i < 7) {  // prefetch next chunk's x; latency hides under the asm
      const int t = (i + 1) * 64 + lane;
      nx1 = x[(b * TT + t) * 16 + f1];
      nx2 = x[(b * TT + t) * 16 + f2i];
    }
    unsigned xaddr = xbase;
    asm volatile(
      "s_mov_b32 s20, 64\n\t"
      "Lstep%=:\n\t"
      // --- broadcast h + this step's x through LDS (same-wave, in-order) ---
      "ds_write_b32 %[laddr], %[h]\n\t"
      "ds_read2_b32 v[38:39], %[xaddr] offset0:0 offset1:64\n\t"
      "ds_read_b128 v[48:51], %[zb]\n\t"
      "ds_read_b128 v[52:55], %[zb] offset:16\n\t"
      "ds_read_b128 v[56:59], %[zb] offset:32\n\t"
      "ds_read_b128 v[60:63], %[zb] offset:48\n\t"
      "ds_read_b128 v[64:67], %[zb] offset:64\n\t"
      "ds_read_b128 v[68:71], %[zb] offset:80\n\t"
      "ds_read_b128 v[72:75], %[zb] offset:96\n\t"
      "ds_read_b128 v[76:79], %[zb] offset:112\n\t"
      "v_add_u32 %[xaddr], 4, %[xaddr]\n\t"
      // wait for write+read2 only; sx math runs under the b128 reads
      "s_waitcnt lgkmcnt(8)\n\t"
      "v_mov_b32 v36, %[bs1]\n\t"
      "v_fmac_f32 v36, v38, %[w11]\n\t"
      "v_fmac_f32 v36, v39, %[w21]\n\t"
      "v_mov_b32 v37, %[bs2]\n\t"
      "v_fmac_f32 v37, v38, %[w12]\n\t"
      "v_fmac_f32 v37, v39, %[w22]\n\t"
      // seed 4 accumulator chains: aA0={sx1,0} aA1=0 aB0={sx2,0} aB1=0
      "v_mov_b32 v40, v36\n\t"
      "v_mov_b32 v41, 0\n\t"
      "v_mov_b32 v42, 0\n\t"
      "v_mov_b32 v43, 0\n\t"
      "v_mov_b32 v44, v37\n\t"
      "v_mov_b32 v45, 0\n\t"
      "v_mov_b32 v46, 0\n\t"
      "v_mov_b32 v47, 0\n\t"
      "s_waitcnt lgkmcnt(0)\n\t"
      // --- 32x v_pk_fma_f32: 64 MACs, 4 interleaved chains (depth 8) ---
      "v_pk_fma_f32 v[40:41], %[wa0],  v[48:49], v[40:41]\n\t"
      "v_pk_fma_f32 v[44:45], %[wb0],  v[48:49], v[44:45]\n\t"
      "v_pk_fma_f32 v[42:43], %[wa1],  v[50:51], v[42:43]\n\t"
      "v_pk_fma_f32 v[46:47], %[wb1],  v[50:51], v[46:47]\n\t"
      "v_pk_fma_f32 v[40:41], %[wa2],  v[52:53], v[40:41]\n\t"
      "v_pk_fma_f32 v[44:45], %[wb2],  v[52:53], v[44:45]\n\t"
      "v_pk_fma_f32 v[42:43], %[wa3],  v[54:55], v[42:43]\n\t"
      "v_pk_fma_f32 v[46:47], %[wb3],  v[54:55], v[46:47]\n\t"
      "v_pk_fma_f32 v[40:41], %[wa4],  v[56:57], v[40:41]\n\t"
      "v_pk_fma_f32 v[44:45], %[wb4],  v[56:57], v[44:45]\n\t"
      "v_pk_fma_f32 v[42:43], %[wa5],  v[58:59], v[42:43]\n\t"
      "v_pk_fma_f32 v[46:47], %[wb5],  v[58:59], v[46:47]\n\t"
      "v_pk_fma_f32 v[40:41], %[wa6],  v[60:61], v[40:41]\n\t"
      "v_pk_fma_f32 v[44:45], %[wb6],  v[60:61], v[44:45]\n\t"
      "v_pk_fma_f32 v[42:43], %[wa7],  v[62:63], v[42:43]\n\t"
      "v_pk_fma_f32 v[46:47], %[wb7],  v[62:63], v[46:47]\n\t"
      "v_pk_fma_f32 v[40:41], %[wa8],  v[64:65], v[40:41]\n\t"
      "v_pk_fma_f32 v[44:45], %[wb8],  v[64:65], v[44:45]\n\t"
      "v_pk_fma_f32 v[42:43], %[wa9],  v[66:67], v[42:43]\n\t"
      "v_pk_fma_f32 v[46:47], %[wb9],  v[66:67], v[46:47]\n\t"
      "v_pk_fma_f32 v[40:41], %[wa10], v[68:69], v[40:41]\n\t"
      "v_pk_fma_f32 v[44:45], %[wb10], v[68:69], v[44:45]\n\t"
      "v_pk_fma_f32 v[42:43], %[wa11], v[70:71], v[42:43]\n\t"
      "v_pk_fma_f32 v[46:47], %[wb11], v[70:71], v[46:47]\n\t"
      "v_pk_fma_f32 v[40:41], %[wa12], v[72:73], v[40:41]\n\t"
      "v_pk_fma_f32 v[44:45], %[wb12], v[72:73], v[44:45]\n\t"
      "v_pk_fma_f32 v[42:43], %[wa13], v[74:75], v[42:43]\n\t"
      "v_pk_fma_f32 v[46:47], %[wb13], v[74:75], v[46:47]\n\t"
      "v_pk_fma_f32 v[40:41], %[wa14], v[76:77], v[40:41]\n\t"
      "v_pk_fma_f32 v[44:45], %[wb14], v[76:77], v[44:45]\n\t"
      "v_pk_fma_f32 v[42:43], %[wa15], v[78:79], v[42:43]\n\t"
      "v_pk_fma_f32 v[46:47], %[wb15], v[78:79], v[46:47]\n\t"
      // --- horizontal reduce + activations ---
      "v_pk_add_f32 v[40:41], v[40:41], v[42:43]\n\t"
      "v_pk_add_f32 v[44:45], v[44:45], v[46:47]\n\t"
      "v_add_f32 v81, v40, v41\n\t"
      "v_add_f32 v82, v44, v45\n\t"
      "v_exp_f32 v81, v81\n\t"
      "v_exp_f32 v82, v82\n\t"
      "s_nop 1\n\t"
      "v_add_f32 v81, 1.0, v81\n\t"
      "v_add_f32 v82, 1.0, v82\n\t"
      // Newton rcp (d in [1,2^30], seed 0x7ef0a3d2, 2 iters): 1/v81, 1/v82
      "v_sub_u32 v87, 0x7ef0a3d2, v81\n\t"
      "v_sub_u32 v88, 0x7ef0a3d2, v82\n\t"
      "v_fma_f32 v80, -v81, v87, 2.0\n\t"
      "v_fma_f32 v89, -v82, v88, 2.0\n\t"
      "v_mul_f32 v87, v87, v80\n\t"
      "v_mul_f32 v88, v88, v89\n\t"
      "v_fma_f32 v80, -v81, v87, 2.0\n\t"
      "v_fma_f32 v89, -v82, v88, 2.0\n\t"
      "v_mul_f32 v81, v87, v80\n\t"
      "v_mul_f32 v82, v88, v89\n\t"
      "v_fma_f32 v81, %[ac1], v81, %[cc1]\n\t"   // g1
      // cross-half exchange (shfl_xor 32)
      "ds_bpermute_b32 v83, %[swz], v81\n\t"     // p1
      "ds_bpermute_b32 v84, %[swz], v82\n\t"     // p2
      "s_waitcnt lgkmcnt(0)\n\t"
      "v_mul_f32 v85, v81, v83\n\t"              // g1*p1
      "v_fma_f32 %[c], v82, %[c], v85\n\t"       // c = g2*c + g1*p1
      "v_mul_f32 v86, 0xc038aa3b, %[c]\n\t"      // -2*log2e * c
      "v_exp_f32 v86, v86\n\t"
      "s_nop 1\n\t"
      "v_add_f32 v86, 1.0, v86\n\t"
      // Newton rcp for tanh(c)
      "v_sub_u32 v87, 0x7ef0a3d2, v86\n\t"
      "v_fma_f32 v80, -v86, v87, 2.0\n\t"
      "v_mul_f32 v87, v87, v80\n\t"
      "v_fma_f32 v80, -v86, v87, 2.0\n\t"
      "v_mul_f32 v86, v87, v80\n\t"
      "v_fma_f32 v86, 2.0, v86, -1.0\n\t"        // tanh(c)
      "v_mul_f32 %[h], v84, v86\n\t"             // h = p2 * tanh(c)
      // per-step store; junk lanes OOB -> dropped by SRD bounds check
      "buffer_store_dword %[h], %[voff], %[srd], 0 offen\n\t"
      "v_add_u32 %[voff], 0xa00, %[voff]\n\t"
      "s_sub_u32 s20, s20, 1\n\t"
      "s_cmp_lg_u32 s20, 0\n\t"
      "s_cbranch_scc1 Lstep%=\n\t"
      : [h]"+v"(h), [c]"+v"(c), [voff]"+v"(voff), [xaddr]"+v"(xaddr)
      : [laddr]"v"(laddr), [zb]"v"(zb), [swz]"v"(swz),
        [w11]"v"(ws11), [w21]"v"(ws21), [bs1]"v"(bs1),
        [w12]"v"(ws12), [w22]"v"(ws22), [bs2]"v"(bs2),
        [ac1]"v"(Ac1), [cc1]"v"(Cc1), [srd]"s"(srd),
        [wa0]"v"(wA[0]),  [wa1]"v"(wA[1]),  [wa2]"v"(wA[2]),  [wa3]"v"(wA[3]),
        [wa4]"v"(wA[4]),  [wa5]"v"(wA[5]),  [wa6]"v"(wA[6]),  [wa7]"v"(wA[7]),
        [wa8]"v"(wA[8]),  [wa9]"v"(wA[9]),  [wa10]"v"(wA[10]),[wa11]"v"(wA[11]),
        [wa12]"v"(wA[12]),[wa13]"v"(wA[13]),[wa14]"v"(wA[14]),[wa15]"v"(wA[15]),
        [wb0]"v"(wB[0]),  [wb1]"v"(wB[1]),  [wb2]"v"(wB[2]),  [wb3]"v"(wB[3]),
        [wb4]"v"(wB[4]),  [wb5]"v"(wB[5]),  [wb6]"v"(wB[6]),  [wb7]"v"(wB[7]),
        [wb8]"v"(wB[8]),  [wb9]"v"(wB[9]),  [wb10]"v"(wB[10]),[wb11]"v"(wB[11]),
        [wb12]"v"(wB[12]),[wb13]"v"(wB[13]),[wb14]"v"(wB[14]),[wb15]"v"(wB[15])
      : "memory", "scc", "s20",
        "v36","v37","v38","v39","v40","v41","v42","v43","v44","v45","v46",
        "v47","v48","v49","v50","v51","v52","v53","v54","v55","v56","v57",
        "v58","v59","v60","v61","v62","v63","v64","v65","v66","v67","v68",
        "v69","v70","v71","v72","v73","v74","v75","v76","v77","v78","v79",
        "v80","v81","v82","v83","v84","v85","v86","v87","v88","v89");
  }

  if (lane < 32) {
    out[BN * TT * HN + b * HN + col] = h;             // h_t
    out[BN * TT * HN + BN * HN + b * HN + col] = c;   // c_t
  }
}

extern "C" void kernel_launch(void* const* d_in, const int* in_sizes, int n_in,
                              void* d_out, int out_size, void* d_ws, size_t ws_size,
                              hipStream_t stream) {
  (void)in_sizes; (void)n_in; (void)d_ws; (void)ws_size; (void)out_size;
  const float* x  = (const float*)d_in[0];
  const float* Ui = (const float*)d_in[1];
  const float* Vi = (const float*)d_in[2];
  const float* bi = (const float*)d_in[3];
  const float* Uf = (const float*)d_in[4];
  const float* Vf = (const float*)d_in[5];
  const float* bf = (const float*)d_in[6];
  const float* Uc = (const float*)d_in[7];
  const float* Vc = (const float*)d_in[8];
  const float* bc = (const float*)d_in[9];
  const float* Uo = (const float*)d_in[10];
  const float* Vo = (const float*)d_in[11];
  const float* bo = (const float*)d_in[12];
  float* out = (float*)d_out;

  dim3 grid(2560);  // one unit per wave -> 10 waves/CU
  dim3 block(64);
  hipLaunchKernelGGL(lstm_kernel, grid, block, 0, stream,
                     x, Ui, Vi, bi, Uf, Vf, bf, Uc, Vc, bc, Uo, Vo, bo, out);
}